// Round 1
// baseline (1954.540 us; speedup 1.0000x reference)
//
#include <hip/hip_runtime.h>

// VQ-VAE codebook lookup: z_e [32,2048,64] f32, codebook [1024,64] f32.
// Out = concat(z_q [65536*64] f32, indices [65536] as f32).
// dist(n,k) = ||x_n||^2 - 2 x_n.c_k + ||c_k||^2  (matches reference formula);
// argmin with first-occurrence tie-break.

#define N_ROWS 65536
#define D 64
#define K_CODES 1024

__global__ __launch_bounds__(256) void c2_kernel(const float* __restrict__ cb,
                                                 float* __restrict__ c2) {
    int c = blockIdx.x * 256 + threadIdx.x;
    if (c >= K_CODES) return;
    const float4* row = (const float4*)(cb + c * D);
    float s0 = 0.f, s1 = 0.f, s2 = 0.f, s3 = 0.f;
#pragma unroll
    for (int i = 0; i < D / 4; ++i) {
        float4 v = row[i];
        s0 = fmaf(v.x, v.x, s0);
        s1 = fmaf(v.y, v.y, s1);
        s2 = fmaf(v.z, v.z, s2);
        s3 = fmaf(v.w, v.w, s3);
    }
    c2[c] = (s0 + s1) + (s2 + s3);
}

// 4 threads per row: thread split s scans codes c = 4*kk + s.
// x row (64 f32) held in VGPRs; codebook streamed from global (L2-resident).
__global__ __launch_bounds__(256) void vq_kernel(const float* __restrict__ z_e,
                                                 const float* __restrict__ cb,
                                                 const float* __restrict__ c2,
                                                 float* __restrict__ out) {
    const int t   = blockIdx.x * 256 + threadIdx.x;
    const int row = t >> 2;
    const int s   = t & 3;

    // Load this row: 16 x float4 = 64 floats in registers.
    const float4* xr = (const float4*)(z_e + row * D);
    float4 x[16];
#pragma unroll
    for (int i = 0; i < 16; ++i) x[i] = xr[i];

    float x2 = 0.f;
    {
        float a = 0.f, b = 0.f, c = 0.f, d = 0.f;
#pragma unroll
        for (int i = 0; i < 16; ++i) {
            a = fmaf(x[i].x, x[i].x, a);
            b = fmaf(x[i].y, x[i].y, b);
            c = fmaf(x[i].z, x[i].z, c);
            d = fmaf(x[i].w, x[i].w, d);
        }
        x2 = (a + b) + (c + d);
    }

    float best = 3.4e38f;
    int   bidx = 0;

#pragma unroll 2
    for (int kk = 0; kk < K_CODES / 4; ++kk) {
        const int c = (kk << 2) | s;
        const float4* cr = (const float4*)(cb + (c << 6));
        float4 a0 = make_float4(0.f, 0.f, 0.f, 0.f);
        float4 a1 = make_float4(0.f, 0.f, 0.f, 0.f);
#pragma unroll
        for (int i = 0; i < 16; i += 2) {
            float4 ca = cr[i];
            float4 cb4 = cr[i + 1];
            a0.x = fmaf(x[i].x, ca.x, a0.x);
            a0.y = fmaf(x[i].y, ca.y, a0.y);
            a0.z = fmaf(x[i].z, ca.z, a0.z);
            a0.w = fmaf(x[i].w, ca.w, a0.w);
            a1.x = fmaf(x[i + 1].x, cb4.x, a1.x);
            a1.y = fmaf(x[i + 1].y, cb4.y, a1.y);
            a1.z = fmaf(x[i + 1].z, cb4.z, a1.z);
            a1.w = fmaf(x[i + 1].w, cb4.w, a1.w);
        }
        float dot = ((a0.x + a0.y) + (a0.z + a0.w)) + ((a1.x + a1.y) + (a1.z + a1.w));
        float dist = fmaf(-2.f, dot, x2 + c2[c]);
        // strict < keeps earliest (ascending c within this split)
        if (dist < best) { best = dist; bidx = c; }
    }

    // Merge (best, bidx) across the 4 split lanes (lanes 4r+0..4r+3).
#pragma unroll
    for (int off = 1; off < 4; off <<= 1) {
        float ob = __shfl_xor(best, off);
        int   oi = __shfl_xor(bidx, off);
        if (ob < best || (ob == best && oi < bidx)) { best = ob; bidx = oi; }
    }

    // Each split lane writes one quarter (16 floats) of z_q row — coalesced.
    const float4* src = (const float4*)(cb + (bidx << 6)) + (s << 2);
    float4*       dst = (float4*)(out + row * D) + (s << 2);
#pragma unroll
    for (int i = 0; i < 4; ++i) dst[i] = src[i];

    if (s == 0) out[N_ROWS * D + row] = (float)bidx;
}

extern "C" void kernel_launch(void* const* d_in, const int* in_sizes, int n_in,
                              void* d_out, int out_size, void* d_ws, size_t ws_size,
                              hipStream_t stream) {
    const float* z_e = (const float*)d_in[0];
    const float* cb  = (const float*)d_in[1];
    float* out = (float*)d_out;
    float* c2  = (float*)d_ws;  // 1024 floats of scratch

    hipLaunchKernelGGL(c2_kernel, dim3(K_CODES / 256), dim3(256), 0, stream, cb, c2);
    hipLaunchKernelGGL(vq_kernel, dim3((N_ROWS * 4) / 256), dim3(256), 0, stream,
                       z_e, cb, c2, out);
}

// Round 2
// 179.917 us; speedup vs baseline: 10.8636x; 10.8636x over previous
//
#include <hip/hip_runtime.h>

// VQ-VAE codebook lookup: z_e [32,2048,64] f32, codebook [1024,64] f32.
// Out = concat(z_q [65536*64] f32, indices [65536] written as f32).
// dist(n,k) = ||x||^2 - 2 x.c + ||c||^2, argmin with first-occurrence tie-break.
//
// GEMM-style tiling: block = 256 threads, 128 rows x full 1024 codes
// (8 chunks of 128). xT/cT staged transposed in LDS with a skewed layout
// (stride 140, col = c + 4*(c>>5)) -> <=2-way bank conflicts everywhere.
// Per-thread micro-tile 8 rows x 8 codes = 64 accumulators (registers).

#define N_ROWS  65536
#define D       64
#define K_CODES 1024
#define M_TILE  128
#define N_CHUNK 128
#define N_CHUNKS (K_CODES / N_CHUNK)
#define STRIDE  140                       // padded LDS row stride (floats)
#define COL(x)  ((x) + 4 * ((x) >> 5))    // skew: max col 127+12=139 < 140

__global__ __launch_bounds__(256) void c2_kernel(const float* __restrict__ cb,
                                                 float* __restrict__ c2) {
    int c = blockIdx.x * 256 + threadIdx.x;
    if (c >= K_CODES) return;
    const float4* row = (const float4*)(cb + c * D);
    float s0 = 0.f, s1 = 0.f, s2 = 0.f, s3 = 0.f;
#pragma unroll
    for (int i = 0; i < D / 4; ++i) {
        float4 v = row[i];
        s0 = fmaf(v.x, v.x, s0);
        s1 = fmaf(v.y, v.y, s1);
        s2 = fmaf(v.z, v.z, s2);
        s3 = fmaf(v.w, v.w, s3);
    }
    c2[c] = (s0 + s1) + (s2 + s3);
}

__global__ __launch_bounds__(256, 2) void vq_kernel(const float* __restrict__ z_e,
                                                    const float* __restrict__ cb,
                                                    const float* __restrict__ c2g,
                                                    float* __restrict__ out) {
    __shared__ float xT[64 * STRIDE];   // [d][row]  35840 B
    __shared__ float cT[64 * STRIDE];   // [d][code] 35840 B
    __shared__ float x2_l[M_TILE];      // 512 B

    const int tid      = threadIdx.x;
    const int row_base = blockIdx.x * M_TILE;
    const int ti = tid >> 4;   // 0..15 : row group (8 rows each)
    const int tj = tid & 15;   // 0..15 : code group (8 codes each)

    // ---- stage xT (transpose z_e tile into LDS) ----
    // thread: rows (tid&15)+16*ii, dim-seg (tid>>4); 16 full 64B lines/wave.
    const int sseg = tid >> 4;       // 0..15 -> dims 4*sseg..4*sseg+3
    const int srow = tid & 15;
#pragma unroll
    for (int ii = 0; ii < 8; ++ii) {
        const int r = srow + 16 * ii;
        float4 v = *(const float4*)(z_e + (size_t)(row_base + r) * D + 4 * sseg);
        const int col = COL(r);
        xT[(4 * sseg + 0) * STRIDE + col] = v.x;
        xT[(4 * sseg + 1) * STRIDE + col] = v.y;
        xT[(4 * sseg + 2) * STRIDE + col] = v.z;
        xT[(4 * sseg + 3) * STRIDE + col] = v.w;
    }
    __syncthreads();

    // ---- x2 for the 128 rows (one-time) ----
    if (tid < M_TILE) {
        const int col = COL(tid);
        float a = 0.f, b = 0.f, c = 0.f, e = 0.f;
#pragma unroll
        for (int d = 0; d < 64; d += 4) {
            float v0 = xT[(d + 0) * STRIDE + col];
            float v1 = xT[(d + 1) * STRIDE + col];
            float v2 = xT[(d + 2) * STRIDE + col];
            float v3 = xT[(d + 3) * STRIDE + col];
            a = fmaf(v0, v0, a);
            b = fmaf(v1, v1, b);
            c = fmaf(v2, v2, c);
            e = fmaf(v3, v3, e);
        }
        x2_l[tid] = (a + b) + (c + e);
    }
    __syncthreads();

    float x2r[8];
#pragma unroll
    for (int r = 0; r < 8; ++r) x2r[r] = x2_l[8 * ti + r];

    float best[8];
    int   bidx[8];
#pragma unroll
    for (int r = 0; r < 8; ++r) { best[r] = 3.4e38f; bidx[r] = 0; }

    const int cxa = COL(8 * ti);      // contiguous 8 floats (within 32-group)
    const int cxb = cxa + 4;
    const int cca = COL(8 * tj);
    const int ccb = cca + 4;

    for (int ch = 0; ch < N_CHUNKS; ++ch) {
        // ---- stage cT chunk (transpose codebook rows into LDS) ----
#pragma unroll
        for (int ii = 0; ii < 8; ++ii) {
            const int c = srow + 16 * ii;
            float4 v = *(const float4*)(cb + (size_t)(ch * N_CHUNK + c) * D + 4 * sseg);
            const int col = COL(c);
            cT[(4 * sseg + 0) * STRIDE + col] = v.x;
            cT[(4 * sseg + 1) * STRIDE + col] = v.y;
            cT[(4 * sseg + 2) * STRIDE + col] = v.z;
            cT[(4 * sseg + 3) * STRIDE + col] = v.w;
        }
        __syncthreads();

        // ---- 8x8 register-tile dot products over depth 64 ----
        float acc[8][8];
#pragma unroll
        for (int r = 0; r < 8; ++r)
#pragma unroll
            for (int q = 0; q < 8; ++q) acc[r][q] = 0.f;

#pragma unroll 4
        for (int d = 0; d < 64; ++d) {
            const float4 xa = *(const float4*)&xT[d * STRIDE + cxa];
            const float4 xb = *(const float4*)&xT[d * STRIDE + cxb];
            const float4 ca = *(const float4*)&cT[d * STRIDE + cca];
            const float4 cb4 = *(const float4*)&cT[d * STRIDE + ccb];
            const float xv[8] = {xa.x, xa.y, xa.z, xa.w, xb.x, xb.y, xb.z, xb.w};
            const float cv[8] = {ca.x, ca.y, ca.z, ca.w, cb4.x, cb4.y, cb4.z, cb4.w};
#pragma unroll
            for (int r = 0; r < 8; ++r)
#pragma unroll
                for (int q = 0; q < 8; ++q)
                    acc[r][q] = fmaf(xv[r], cv[q], acc[r][q]);
        }

        // ---- fused distance + running argmin ----
        const float4 c20 = *(const float4*)(c2g + ch * N_CHUNK + 8 * tj);
        const float4 c21 = *(const float4*)(c2g + ch * N_CHUNK + 8 * tj + 4);
        const float c2v[8] = {c20.x, c20.y, c20.z, c20.w, c21.x, c21.y, c21.z, c21.w};
#pragma unroll
        for (int q = 0; q < 8; ++q) {
            const int code = ch * N_CHUNK + 8 * tj + q;
#pragma unroll
            for (int r = 0; r < 8; ++r) {
                const float dist = fmaf(-2.f, acc[r][q], x2r[r] + c2v[q]);
                if (dist < best[r]) { best[r] = dist; bidx[r] = code; }
            }
        }
        __syncthreads();   // before next chunk overwrites cT
    }

    // ---- reduce (best, idx) across the 16 lanes sharing this row group ----
#pragma unroll
    for (int off = 1; off < 16; off <<= 1) {
#pragma unroll
        for (int r = 0; r < 8; ++r) {
            const float ob = __shfl_xor(best[r], off);
            const int   oi = __shfl_xor(bidx[r], off);
            if (ob < best[r] || (ob == best[r] && oi < bidx[r])) {
                best[r] = ob; bidx[r] = oi;
            }
        }
    }

    // ---- write z_q (coalesced float4) and indices ----
#pragma unroll
    for (int r = 0; r < 8; ++r) {
        const int row = row_base + 8 * ti + r;
        const float4 v = *(const float4*)(cb + (size_t)bidx[r] * D + 4 * tj);
        *(float4*)(out + (size_t)row * D + 4 * tj) = v;
    }
    if (tj < 8) out[(size_t)N_ROWS * D + row_base + 8 * ti + tj] = (float)bidx[tj];
}

extern "C" void kernel_launch(void* const* d_in, const int* in_sizes, int n_in,
                              void* d_out, int out_size, void* d_ws, size_t ws_size,
                              hipStream_t stream) {
    const float* z_e = (const float*)d_in[0];
    const float* cb  = (const float*)d_in[1];
    float* out = (float*)d_out;
    float* c2  = (float*)d_ws;  // 1024 floats scratch

    hipLaunchKernelGGL(c2_kernel, dim3(K_CODES / 256), dim3(256), 0, stream, cb, c2);
    hipLaunchKernelGGL(vq_kernel, dim3(N_ROWS / M_TILE), dim3(256), 0, stream,
                       z_e, cb, c2, out);
}